// Round 3
// baseline (238.995 us; speedup 1.0000x reference)
//
#include <hip/hip_runtime.h>
#include <math.h>

#define SEQ 65536
#define FEAT 512
#define NCH 256
#define CHUNK 256
#define THRES1 0.8f
#define THRES_UP 0.5f
#define NEGINF -1e30f

// ---- L1: a = sigmoid(h @ W + b). 16 lanes per row, 4 rows per wave.
//          Lane s of row-group g reads float4 index s + 16*j  -> each load
//          instruction covers four contiguous 256-B runs (full cache lines,
//          fully consumed), vs the previous 16-B-at-128-B-stride scatter.
//          Reduce is 4 shfl_xor steps (within 16-lane groups) vs 6.
//          Blocks 0..255 also do the per-chunk local scans; block 0 zeroes
//          loss/cnt. Grid: SEQ / 16 = 4096 blocks.
__global__ __launch_bounds__(256) void k_matvec_local(
        const float* __restrict__ h, const float* __restrict__ W,
        const float* __restrict__ b, const float* __restrict__ u_pred,
        const float* __restrict__ label,
        float* __restrict__ a,
        float* __restrict__ m_loc, int* __restrict__ openA,
        int* __restrict__ ltLoc, int* __restrict__ lfExcl,
        float* __restrict__ lastm, int* __restrict__ lastopen,
        int* __restrict__ lastgate, int* __restrict__ trigLast,
        int* __restrict__ fallLast, float* __restrict__ losscnt) {
    // ---- matvec part (all blocks) ----
    {
        int wave = threadIdx.x >> 6;
        int lane = threadIdx.x & 63;
        int g    = lane >> 4;        // row within the wave's 4-row group
        int s    = lane & 15;        // 16 lanes cooperate on one row
        int row  = blockIdx.x * 16 + wave * 4 + g;
        const float4* hp = (const float4*)(h + (size_t)row * FEAT);
        const float4* wp = (const float4*)W;
        // 8 float4 per lane, stride 16 float4s: per instruction the wave
        // reads 4 contiguous 256-B runs (one per row group).
        float4 h0 = hp[s],       h1 = hp[s + 16],  h2 = hp[s + 32],  h3 = hp[s + 48];
        float4 h4 = hp[s + 64],  h5 = hp[s + 80],  h6 = hp[s + 96],  h7 = hp[s + 112];
        float4 w0 = wp[s],       w1 = wp[s + 16],  w2 = wp[s + 32],  w3 = wp[s + 48];
        float4 w4 = wp[s + 64],  w5 = wp[s + 80],  w6 = wp[s + 96],  w7 = wp[s + 112];
        float bb = b[0];
        float acc0 = h0.x * w0.x + h0.y * w0.y + h0.z * w0.z + h0.w * w0.w
                   + h2.x * w2.x + h2.y * w2.y + h2.z * w2.z + h2.w * w2.w
                   + h4.x * w4.x + h4.y * w4.y + h4.z * w4.z + h4.w * w4.w
                   + h6.x * w6.x + h6.y * w6.y + h6.z * w6.z + h6.w * w6.w;
        float acc1 = h1.x * w1.x + h1.y * w1.y + h1.z * w1.z + h1.w * w1.w
                   + h3.x * w3.x + h3.y * w3.y + h3.z * w3.z + h3.w * w3.w
                   + h5.x * w5.x + h5.y * w5.y + h5.z * w5.z + h5.w * w5.w
                   + h7.x * w7.x + h7.y * w7.y + h7.z * w7.z + h7.w * w7.w;
        float acc = acc0 + acc1;
        #pragma unroll
        for (int m = 8; m; m >>= 1) acc += __shfl_xor(acc, m, 64);
        if (s == 0) a[row] = 1.0f / (1.0f + expf(-(acc + bb)));
    }
    if (blockIdx.x == 0 && threadIdx.x == 0) { losscnt[0] = 0.0f; losscnt[1] = 0.0f; }
    // ---- local scans (blocks 0..255 only; block-uniform branch) ----
    if (blockIdx.x < NCH) {
        __shared__ float su[256];
        __shared__ float sm[256];
        __shared__ int   sr[256];
        __shared__ int   st[256];
        __shared__ int   sf[256];
        int t = threadIdx.x, c = blockIdx.x;
        int i = c * CHUNK + t;
        float u = u_pred[i];
        su[t] = u;
        __syncthreads();
        bool gate = u >= THRES_UP;
        bool gprevLocal = (t > 0) && (su[t - 1] >= THRES_UP);
        bool gprev = (t > 0) ? gprevLocal : ((i > 0) && (u_pred[i - 1] >= THRES_UP));
        bool fall = gprev && !gate;
        bool trig = label[i] >= THRES1;

        sm[t] = gate ? u : NEGINF;                               // segmented run-max
        sr[t] = gate ? ((t > 0 && !gprevLocal) ? 1 : 0) : 1;     // boundary flag
        st[t] = trig ? i : -1;                                   // last trigger idx
        sf[t] = fall ? i : -1;                                   // last fall idx
        __syncthreads();
        for (int d = 1; d < 256; d <<= 1) {
            float lm = NEGINF; int lr = 0, lt = -1, lf = -1;
            bool act = t >= d;
            if (act) { lm = sm[t - d]; lr = sr[t - d]; lt = st[t - d]; lf = sf[t - d]; }
            __syncthreads();
            if (act) {
                if (!sr[t]) sm[t] = fmaxf(lm, sm[t]);
                sr[t] |= lr;
                st[t] = max(st[t], lt);
                sf[t] = max(sf[t], lf);
            }
            __syncthreads();
        }
        m_loc[i]  = sm[t];
        openA[i]  = (sr[t] == 0 && gate) ? 1 : 0;
        ltLoc[i]  = st[t];
        lfExcl[i] = (t == 0) ? -1 : sf[t - 1];
        if (t == 255) {
            lastm[c]    = sm[255];
            lastopen[c] = (sr[255] == 0 && gate) ? 1 : 0;
            lastgate[c] = gate ? 1 : 0;
            trigLast[c] = st[255];
            fallLast[c] = sf[255];
        }
    }
}

// ---- L2: redundant cross-chunk max-plus scan -> inc_c; finalize up_hat;
//          per-chunk affine scan of alpha pairs ----
__global__ __launch_bounds__(256) void k_uphat_alpha(
        const float* __restrict__ u_pred, const float* __restrict__ a,
        const float* __restrict__ m_loc, const int* __restrict__ openA,
        const float* __restrict__ lastm, const int* __restrict__ lastopen,
        const int* __restrict__ lastgate,
        float* __restrict__ Pc, float* __restrict__ Qc,
        float* __restrict__ Pch, float* __restrict__ Qch,
        float* __restrict__ out) {
    __shared__ float sc[256], sd[256];
    int t = threadIdx.x, c = blockIdx.x;
    int i = c * CHUNK + t;

    // redundant max-plus scan over chunk summaries (each block computes all)
    {
        bool lg = lastgate[t] != 0;
        sc[t] = lg ? lastm[t] : NEGINF;                 // A
        sd[t] = (lg && lastopen[t]) ? 0.0f : NEGINF;    // B
    }
    __syncthreads();
    for (int d = 1; d < 256; d <<= 1) {
        float lA = NEGINF, lB = NEGINF;
        bool act = t >= d;
        if (act) { lA = sc[t - d]; lB = sd[t - d]; }
        __syncthreads();
        if (act) {
            float nA = fmaxf(sc[t], sd[t] + lA);   // max-plus compose right∘left
            float nB = fmaxf(sd[t] + lB, NEGINF);
            sc[t] = nA; sd[t] = nB;
        }
        __syncthreads();
    }
    float inc_c = (c == 0) ? NEGINF : sc[c - 1];
    __syncthreads();

    float u = u_pred[i];
    bool gate = u >= THRES_UP;
    float uh = gate ? (openA[i] ? fmaxf(m_loc[i], inc_c) : m_loc[i]) : u;
    out[3 * SEQ + i] = uh;   // up_hats
    out[2 * SEQ + i] = u;    // u_pred passthrough
    sc[t] = uh;
    sd[t] = (1.0f - uh) * a[i];
    __syncthreads();
    for (int d = 1; d < 256; d <<= 1) {
        float lc = 1.0f, ld = 0.0f;
        bool act = t >= d;
        if (act) { lc = sc[t - d]; ld = sd[t - d]; }
        __syncthreads();
        if (act) { sd[t] = sc[t] * ld + sd[t]; sc[t] = sc[t] * lc; }
        __syncthreads();
    }
    Pc[i] = sc[t];
    Qc[i] = sd[t];
    if (t == 255) { Pch[c] = sc[255]; Qch[c] = sd[255]; }
}

// ---- L3: redundant affine scan of Pch/Qch -> alphaIn_c; finalize alpha;
//          per-chunk affine scan of y pairs (into Pc/Qc as Ec/Fc) ----
__global__ __launch_bounds__(256) void k_alpha_y(
        float* __restrict__ Pc, float* __restrict__ Qc,
        const float* __restrict__ Pch, const float* __restrict__ Qch,
        float* __restrict__ out,
        float* __restrict__ Ech, float* __restrict__ Fch) {
    __shared__ float sc[256], sd[256];
    int t = threadIdx.x, c = blockIdx.x;
    int i = c * CHUNK + t;

    sc[t] = Pch[t]; sd[t] = Qch[t];
    __syncthreads();
    for (int d = 1; d < 256; d <<= 1) {
        float lc = 1.0f, ld = 0.0f;
        bool act = t >= d;
        if (act) { lc = sc[t - d]; ld = sd[t - d]; }
        __syncthreads();
        if (act) { sd[t] = sc[t] * ld + sd[t]; sc[t] = sc[t] * lc; }
        __syncthreads();
    }
    float alphaIn_c = (c == 0) ? 0.0f : sd[c - 1];
    __syncthreads();

    float al = Pc[i] * alphaIn_c + Qc[i];
    out[SEQ + i] = al;  // alphas
    float uh = out[3 * SEQ + i];
    bool gate = uh >= THRES_UP;
    sc[t] = gate ? (1.0f - al) : 0.0f;
    sd[t] = gate ? al * uh : 0.0f;
    __syncthreads();
    for (int d = 1; d < 256; d <<= 1) {
        float lc = 1.0f, ld = 0.0f;
        bool act = t >= d;
        if (act) { lc = sc[t - d]; ld = sd[t - d]; }
        __syncthreads();
        if (act) { sd[t] = sc[t] * ld + sd[t]; sc[t] = sc[t] * lc; }
        __syncthreads();
    }
    Pc[i] = sc[t];  // Ec
    Qc[i] = sd[t];  // Fc
    if (t == 255) { Ech[c] = sc[255]; Fch[c] = sd[255]; }
}

// ---- L4: redundant affine scan of Ech/Fch (full y-prefix in LDS) + redundant
//          max scans of trigLast/fallLast; finalize y; loss/cnt ----
__global__ __launch_bounds__(256) void k_yfinal_loss(
        const float* __restrict__ Ec, const float* __restrict__ Fc,
        const float* __restrict__ Ech, const float* __restrict__ Fch,
        const int* __restrict__ trigLast, const int* __restrict__ fallLast,
        const float* __restrict__ u_pred, const float* __restrict__ label,
        const float* __restrict__ thres2,
        const int* __restrict__ ltLoc, const int* __restrict__ lfExcl,
        float* __restrict__ out) {
    __shared__ float sc[256], sd[256], syIn[256];
    __shared__ int   st[256], sf[256];
    int t = threadIdx.x, c = blockIdx.x;
    int i = c * CHUNK + t;

    sc[t] = Ech[t]; sd[t] = Fch[t];
    st[t] = trigLast[t]; sf[t] = fallLast[t];
    __syncthreads();
    for (int d = 1; d < 256; d <<= 1) {
        float lc = 1.0f, ld = 0.0f; int lt = -1, lf = -1;
        bool act = t >= d;
        if (act) { lc = sc[t - d]; ld = sd[t - d]; lt = st[t - d]; lf = sf[t - d]; }
        __syncthreads();
        if (act) {
            sd[t] = sc[t] * ld + sd[t]; sc[t] = sc[t] * lc;
            st[t] = max(st[t], lt);
            sf[t] = max(sf[t], lf);
        }
        __syncthreads();
    }
    syIn[t] = (t == 0) ? 0.0f : sd[t - 1];   // incoming y for chunk t
    int trigIn_c = (c == 0) ? -1 : st[c - 1];
    int fallIn_c = (c == 0) ? -1 : sf[c - 1];
    __syncthreads();

    out[i] = Ec[i] * syIn[c] + Fc[i];  // ys

    float u = u_pred[i];
    bool gate = u >= THRES_UP;
    bool gprev = (i > 0) && (u_pred[i - 1] >= THRES_UP);
    bool fall = gprev && !gate;
    float contrib = 0.0f;
    int flag = 0;
    if (fall) {
        int j  = max(ltLoc[i], trigIn_c);    // last label-trigger <= i
        int pf = max(lfExcl[i], fallIn_c);   // last fall < i
        float lc = 0.0f;
        if (j > pf) {
            bool gj = u_pred[j] >= THRES_UP;
            float yj = Ec[j] * syIn[j >> 8] + Fc[j];
            float d = yj - label[j];
            lc = gj ? d * d : -1.0f;
        }
        bool isneg = (lc == -1.0f);
        bool nonzero = (lc != 0.0f);
        if (!isneg) {
            if (nonzero) { contrib = lc; flag = 1; }   // * R, R = 1.0
            else {
                int ip = i - 1;
                float ypre = Ec[ip] * syIn[ip >> 8] + Fc[ip];
                if (ypre >= THRES1) {
                    float t2 = thres2[(i < 59) ? i : 59];
                    float d2 = ypre - t2;
                    contrib = d2 * d2; flag = 1;
                }
            }
        }
    }
    #pragma unroll
    for (int off = 32; off; off >>= 1) {
        contrib += __shfl_down(contrib, off, 64);
        flag    += __shfl_down(flag, off, 64);
    }
    if ((t & 63) == 0 && (contrib != 0.0f || flag != 0)) {
        atomicAdd(&out[4 * SEQ], contrib);
        atomicAdd(&out[4 * SEQ + 1], (float)flag);
    }
}

extern "C" void kernel_launch(void* const* d_in, const int* in_sizes, int n_in,
                              void* d_out, int out_size, void* d_ws, size_t ws_size,
                              hipStream_t stream) {
    const float* h      = (const float*)d_in[0];
    const float* W      = (const float*)d_in[1];
    const float* b      = (const float*)d_in[2];
    const float* u_pred = (const float*)d_in[4];
    const float* label  = (const float*)d_in[5];
    const float* thres2 = (const float*)d_in[6];
    float* out  = (float*)d_out;
    float* base = (float*)d_ws;

    float* a      = base;
    float* m_loc  = base + SEQ;
    float* Pc     = base + 2 * (size_t)SEQ;
    float* Qc     = base + 3 * (size_t)SEQ;
    int*   openA  = (int*)(base + 4 * (size_t)SEQ);
    int*   ltLoc  = (int*)(base + 5 * (size_t)SEQ);
    int*   lfExcl = (int*)(base + 6 * (size_t)SEQ);
    float* sums   = base + 7 * (size_t)SEQ;
    float* lastm   = sums;
    float* Pch     = sums + NCH;
    float* Qch     = sums + 2 * NCH;
    float* Ech     = sums + 3 * NCH;
    float* Fch     = sums + 4 * NCH;
    int*   lastopen = (int*)(sums + 5 * NCH);
    int*   lastgate = (int*)(sums + 6 * NCH);
    int*   trigLast = (int*)(sums + 7 * NCH);
    int*   fallLast = (int*)(sums + 8 * NCH);

    k_matvec_local<<<SEQ / 16, 256, 0, stream>>>(h, W, b, u_pred, label, a,
                                                 m_loc, openA, ltLoc, lfExcl,
                                                 lastm, lastopen, lastgate, trigLast, fallLast,
                                                 out + 4 * SEQ);
    k_uphat_alpha<<<NCH, CHUNK, 0, stream>>>(u_pred, a, m_loc, openA,
                                             lastm, lastopen, lastgate,
                                             Pc, Qc, Pch, Qch, out);
    k_alpha_y<<<NCH, CHUNK, 0, stream>>>(Pc, Qc, Pch, Qch, out, Ech, Fch);
    k_yfinal_loss<<<NCH, CHUNK, 0, stream>>>(Pc, Qc, Ech, Fch, trigLast, fallLast,
                                             u_pred, label, thres2, ltLoc, lfExcl, out);
}

// Round 6
// 226.517 us; speedup vs baseline: 1.0551x; 1.0551x over previous
//
#include <hip/hip_runtime.h>
#include <math.h>

#define SEQ 65536
#define FEAT 512
#define NCH 256
#define CHUNK 256
#define THRES1 0.8f
#define THRES_UP 0.5f
#define NEGINF -1e30f

typedef float v4f __attribute__((ext_vector_type(4)));

// ---- L1: a = sigmoid(h @ W + b). 16 lanes per row, 4 rows per wave.
//          h loads are nontemporal (streamed once, keep L2 for small arrays).
//          Blocks 0..255 also do the per-chunk local scans; block 0 zeroes
//          loss/cnt. Grid: SEQ / 16 = 4096 blocks.
__global__ __launch_bounds__(256) void k_matvec_local(
        const float* __restrict__ h, const float* __restrict__ W,
        const float* __restrict__ b, const float* __restrict__ u_pred,
        const float* __restrict__ label,
        float* __restrict__ a,
        float* __restrict__ m_loc, int* __restrict__ openA,
        int* __restrict__ ltLoc, int* __restrict__ lfExcl,
        float* __restrict__ lastm, int* __restrict__ lastopen,
        int* __restrict__ lastgate, int* __restrict__ trigLast,
        int* __restrict__ fallLast, float* __restrict__ losscnt) {
    // ---- matvec part (all blocks) ----
    {
        int wave = threadIdx.x >> 6;
        int lane = threadIdx.x & 63;
        int g    = lane >> 4;        // row within the wave's 4-row group
        int s    = lane & 15;        // 16 lanes cooperate on one row
        int row  = blockIdx.x * 16 + wave * 4 + g;
        const v4f* hp = (const v4f*)(h + (size_t)row * FEAT);
        const v4f* wp = (const v4f*)W;
        v4f h0 = __builtin_nontemporal_load(hp + s);
        v4f h1 = __builtin_nontemporal_load(hp + s + 16);
        v4f h2 = __builtin_nontemporal_load(hp + s + 32);
        v4f h3 = __builtin_nontemporal_load(hp + s + 48);
        v4f h4 = __builtin_nontemporal_load(hp + s + 64);
        v4f h5 = __builtin_nontemporal_load(hp + s + 80);
        v4f h6 = __builtin_nontemporal_load(hp + s + 96);
        v4f h7 = __builtin_nontemporal_load(hp + s + 112);
        v4f w0 = wp[s],       w1 = wp[s + 16],  w2 = wp[s + 32],  w3 = wp[s + 48];
        v4f w4 = wp[s + 64],  w5 = wp[s + 80],  w6 = wp[s + 96],  w7 = wp[s + 112];
        float bb = b[0];
        float acc0 = h0.x * w0.x + h0.y * w0.y + h0.z * w0.z + h0.w * w0.w
                   + h2.x * w2.x + h2.y * w2.y + h2.z * w2.z + h2.w * w2.w
                   + h4.x * w4.x + h4.y * w4.y + h4.z * w4.z + h4.w * w4.w
                   + h6.x * w6.x + h6.y * w6.y + h6.z * w6.z + h6.w * w6.w;
        float acc1 = h1.x * w1.x + h1.y * w1.y + h1.z * w1.z + h1.w * w1.w
                   + h3.x * w3.x + h3.y * w3.y + h3.z * w3.z + h3.w * w3.w
                   + h5.x * w5.x + h5.y * w5.y + h5.z * w5.z + h5.w * w5.w
                   + h7.x * w7.x + h7.y * w7.y + h7.z * w7.z + h7.w * w7.w;
        float acc = acc0 + acc1;
        #pragma unroll
        for (int m = 8; m; m >>= 1) acc += __shfl_xor(acc, m, 64);
        if (s == 0) a[row] = 1.0f / (1.0f + expf(-(acc + bb)));
    }
    if (blockIdx.x == 0 && threadIdx.x == 0) { losscnt[0] = 0.0f; losscnt[1] = 0.0f; }
    // ---- local scans (blocks 0..255 only; block-uniform branch) ----
    if (blockIdx.x < NCH) {
        __shared__ float su[256];
        __shared__ float sm[256];
        __shared__ int   sr[256];
        __shared__ int   st[256];
        __shared__ int   sf[256];
        int t = threadIdx.x, c = blockIdx.x;
        int i = c * CHUNK + t;
        float u = u_pred[i];
        su[t] = u;
        __syncthreads();
        bool gate = u >= THRES_UP;
        bool gprevLocal = (t > 0) && (su[t - 1] >= THRES_UP);
        bool gprev = (t > 0) ? gprevLocal : ((i > 0) && (u_pred[i - 1] >= THRES_UP));
        bool fall = gprev && !gate;
        bool trig = label[i] >= THRES1;

        sm[t] = gate ? u : NEGINF;                               // segmented run-max
        sr[t] = gate ? ((t > 0 && !gprevLocal) ? 1 : 0) : 1;     // boundary flag
        st[t] = trig ? i : -1;                                   // last trigger idx
        sf[t] = fall ? i : -1;                                   // last fall idx
        __syncthreads();
        for (int d = 1; d < 256; d <<= 1) {
            float lm = NEGINF; int lr = 0, lt = -1, lf = -1;
            bool act = t >= d;
            if (act) { lm = sm[t - d]; lr = sr[t - d]; lt = st[t - d]; lf = sf[t - d]; }
            __syncthreads();
            if (act) {
                if (!sr[t]) sm[t] = fmaxf(lm, sm[t]);
                sr[t] |= lr;
                st[t] = max(st[t], lt);
                sf[t] = max(sf[t], lf);
            }
            __syncthreads();
        }
        m_loc[i]  = sm[t];
        openA[i]  = (sr[t] == 0 && gate) ? 1 : 0;
        ltLoc[i]  = st[t];
        lfExcl[i] = (t == 0) ? -1 : sf[t - 1];
        if (t == 255) {
            lastm[c]    = sm[255];
            lastopen[c] = (sr[255] == 0 && gate) ? 1 : 0;
            lastgate[c] = gate ? 1 : 0;
            trigLast[c] = st[255];
            fallLast[c] = sf[255];
        }
    }
}

// ---- L2: redundant cross-chunk max-plus scan (wave-shfl) -> inc_c; finalize
//          up_hat; per-chunk affine scan (wave-shfl) of alpha pairs ----
__global__ __launch_bounds__(256) void k_uphat_alpha(
        const float* __restrict__ u_pred, const float* __restrict__ a,
        const float* __restrict__ m_loc, const int* __restrict__ openA,
        const float* __restrict__ lastm, const int* __restrict__ lastopen,
        const int* __restrict__ lastgate,
        float* __restrict__ Pc, float* __restrict__ Qc,
        float* __restrict__ Pch, float* __restrict__ Qch,
        float* __restrict__ out) {
    __shared__ float scanA[256];
    __shared__ float wA[4], wB[4];
    int t = threadIdx.x, c = blockIdx.x;
    int lane = t & 63, w = t >> 6;
    int i = c * CHUNK + t;

    // ---- phase 1: max-plus scan over chunk summaries (all blocks redundant)
    {
        bool lg = lastgate[t] != 0;
        float A = lg ? lastm[t] : NEGINF;
        float B = (lg && lastopen[t]) ? 0.0f : NEGINF;
        #pragma unroll
        for (int off = 1; off < 64; off <<= 1) {
            float lA = __shfl_up(A, off, 64);
            float lB = __shfl_up(B, off, 64);
            if (lane >= off) { A = fmaxf(A, B + lA); B = fmaxf(B + lB, NEGINF); }
        }
        if (lane == 63) { wA[w] = A; wB[w] = B; }
        __syncthreads();
        float PA = NEGINF, PB = 0.0f;
        #pragma unroll
        for (int ww = 0; ww < 3; ++ww)
            if (ww < w) { float tA = wA[ww], tB = wB[ww];
                PA = fmaxf(tA, tB + PA); PB = fmaxf(tB + PB, NEGINF); }
        A = fmaxf(A, B + PA);
        scanA[t] = A;
        __syncthreads();
    }
    float inc_c = (c == 0) ? NEGINF : scanA[c - 1];

    // ---- finalize up_hat + per-chunk alpha affine scan
    float u = u_pred[i];
    bool gate = u >= THRES_UP;
    float uh = gate ? (openA[i] ? fmaxf(m_loc[i], inc_c) : m_loc[i]) : u;
    out[3 * SEQ + i] = uh;   // up_hats
    out[2 * SEQ + i] = u;    // u_pred passthrough
    float cc = uh;
    float dd = (1.0f - uh) * a[i];
    #pragma unroll
    for (int off = 1; off < 64; off <<= 1) {
        float lc = __shfl_up(cc, off, 64);
        float ld = __shfl_up(dd, off, 64);
        if (lane >= off) { dd = cc * ld + dd; cc = cc * lc; }
    }
    if (lane == 63) { wA[w] = cc; wB[w] = dd; }
    __syncthreads();
    {
        float pc = 1.0f, pd = 0.0f;
        #pragma unroll
        for (int ww = 0; ww < 3; ++ww)
            if (ww < w) { float tc = wA[ww], td = wB[ww];
                pd = tc * pd + td; pc = tc * pc; }
        dd = cc * pd + dd; cc = cc * pc;
    }
    Pc[i] = cc;
    Qc[i] = dd;
    if (t == 255) { Pch[c] = cc; Qch[c] = dd; }
}

// ---- L3: redundant affine scan of Pch/Qch (wave-shfl) -> alphaIn_c; finalize
//          alpha; per-chunk affine scan of y pairs (into Pc/Qc as Ec/Fc) ----
__global__ __launch_bounds__(256) void k_alpha_y(
        float* __restrict__ Pc, float* __restrict__ Qc,
        const float* __restrict__ Pch, const float* __restrict__ Qch,
        float* __restrict__ out,
        float* __restrict__ Ech, float* __restrict__ Fch) {
    __shared__ float scanD[256];
    __shared__ float wA[4], wB[4];
    int t = threadIdx.x, c = blockIdx.x;
    int lane = t & 63, w = t >> 6;
    int i = c * CHUNK + t;

    // ---- phase 1: affine scan of chunk summaries
    {
        float cc = Pch[t], dd = Qch[t];
        #pragma unroll
        for (int off = 1; off < 64; off <<= 1) {
            float lc = __shfl_up(cc, off, 64);
            float ld = __shfl_up(dd, off, 64);
            if (lane >= off) { dd = cc * ld + dd; cc = cc * lc; }
        }
        if (lane == 63) { wA[w] = cc; wB[w] = dd; }
        __syncthreads();
        float pc = 1.0f, pd = 0.0f;
        #pragma unroll
        for (int ww = 0; ww < 3; ++ww)
            if (ww < w) { float tc = wA[ww], td = wB[ww];
                pd = tc * pd + td; pc = tc * pc; }
        dd = cc * pd + dd;
        scanD[t] = dd;
        __syncthreads();
    }
    float alphaIn_c = (c == 0) ? 0.0f : scanD[c - 1];

    float al = Pc[i] * alphaIn_c + Qc[i];
    out[SEQ + i] = al;  // alphas
    float uh = out[3 * SEQ + i];
    bool gate = uh >= THRES_UP;
    float cc = gate ? (1.0f - al) : 0.0f;
    float dd = gate ? al * uh : 0.0f;
    #pragma unroll
    for (int off = 1; off < 64; off <<= 1) {
        float lc = __shfl_up(cc, off, 64);
        float ld = __shfl_up(dd, off, 64);
        if (lane >= off) { dd = cc * ld + dd; cc = cc * lc; }
    }
    if (lane == 63) { wA[w] = cc; wB[w] = dd; }
    __syncthreads();
    {
        float pc = 1.0f, pd = 0.0f;
        #pragma unroll
        for (int ww = 0; ww < 3; ++ww)
            if (ww < w) { float tc = wA[ww], td = wB[ww];
                pd = tc * pd + td; pc = tc * pc; }
        dd = cc * pd + dd; cc = cc * pc;
    }
    Pc[i] = cc;  // Ec
    Qc[i] = dd;  // Fc
    if (t == 255) { Ech[c] = cc; Fch[c] = dd; }
}

// ---- L4: redundant combined scan (affine + 2 int-max) of chunk summaries
//          (wave-shfl); finalize y; loss/cnt ----
__global__ __launch_bounds__(256) void k_yfinal_loss(
        const float* __restrict__ Ec, const float* __restrict__ Fc,
        const float* __restrict__ Ech, const float* __restrict__ Fch,
        const int* __restrict__ trigLast, const int* __restrict__ fallLast,
        const float* __restrict__ u_pred, const float* __restrict__ label,
        const float* __restrict__ thres2,
        const int* __restrict__ ltLoc, const int* __restrict__ lfExcl,
        float* __restrict__ out) {
    __shared__ float sdArr[256];
    __shared__ int   stArr[256], sfArr[256];
    __shared__ float wC[4], wD[4];
    __shared__ int   wT[4], wF[4];
    int t = threadIdx.x, c = blockIdx.x;
    int lane = t & 63, w = t >> 6;
    int i = c * CHUNK + t;

    {
        float cc = Ech[t], dd = Fch[t];
        int   T = trigLast[t], F = fallLast[t];
        #pragma unroll
        for (int off = 1; off < 64; off <<= 1) {
            float lc = __shfl_up(cc, off, 64);
            float ld = __shfl_up(dd, off, 64);
            int   lt = __shfl_up(T, off, 64);
            int   lf = __shfl_up(F, off, 64);
            if (lane >= off) {
                dd = cc * ld + dd; cc = cc * lc;
                T = max(T, lt); F = max(F, lf);
            }
        }
        if (lane == 63) { wC[w] = cc; wD[w] = dd; wT[w] = T; wF[w] = F; }
        __syncthreads();
        float pc = 1.0f, pd = 0.0f; int pT = -1, pF = -1;
        #pragma unroll
        for (int ww = 0; ww < 3; ++ww)
            if (ww < w) { float tc = wC[ww], td = wD[ww];
                pd = tc * pd + td; pc = tc * pc;
                pT = max(pT, wT[ww]); pF = max(pF, wF[ww]); }
        dd = cc * pd + dd;
        T = max(T, pT); F = max(F, pF);
        sdArr[t] = dd; stArr[t] = T; sfArr[t] = F;
        __syncthreads();
    }
    int trigIn_c = (c == 0) ? -1 : stArr[c - 1];
    int fallIn_c = (c == 0) ? -1 : sfArr[c - 1];
    // incoming y for chunk x: x==0 ? 0 : sdArr[x-1]
    float yIn_c = (c == 0) ? 0.0f : sdArr[c - 1];

    out[i] = Ec[i] * yIn_c + Fc[i];  // ys

    float u = u_pred[i];
    bool gate = u >= THRES_UP;
    bool gprev = (i > 0) && (u_pred[i - 1] >= THRES_UP);
    bool fall = gprev && !gate;
    float contrib = 0.0f;
    int flag = 0;
    if (fall) {
        int j  = max(ltLoc[i], trigIn_c);    // last label-trigger <= i
        int pf = max(lfExcl[i], fallIn_c);   // last fall < i
        float lc = 0.0f;
        if (j > pf) {
            bool gj = u_pred[j] >= THRES_UP;
            int cj = j >> 8;
            float yInj = (cj == 0) ? 0.0f : sdArr[cj - 1];
            float yj = Ec[j] * yInj + Fc[j];
            float d = yj - label[j];
            lc = gj ? d * d : -1.0f;
        }
        bool isneg = (lc == -1.0f);
        bool nonzero = (lc != 0.0f);
        if (!isneg) {
            if (nonzero) { contrib = lc; flag = 1; }   // * R, R = 1.0
            else {
                int ip = i - 1;
                int cp = ip >> 8;
                float yInp = (cp == 0) ? 0.0f : sdArr[cp - 1];
                float ypre = Ec[ip] * yInp + Fc[ip];
                if (ypre >= THRES1) {
                    float t2 = thres2[(i < 59) ? i : 59];
                    float d2 = ypre - t2;
                    contrib = d2 * d2; flag = 1;
                }
            }
        }
    }
    #pragma unroll
    for (int off = 32; off; off >>= 1) {
        contrib += __shfl_down(contrib, off, 64);
        flag    += __shfl_down(flag, off, 64);
    }
    if ((t & 63) == 0 && (contrib != 0.0f || flag != 0)) {
        atomicAdd(&out[4 * SEQ], contrib);
        atomicAdd(&out[4 * SEQ + 1], (float)flag);
    }
}

extern "C" void kernel_launch(void* const* d_in, const int* in_sizes, int n_in,
                              void* d_out, int out_size, void* d_ws, size_t ws_size,
                              hipStream_t stream) {
    const float* h      = (const float*)d_in[0];
    const float* W      = (const float*)d_in[1];
    const float* b      = (const float*)d_in[2];
    const float* u_pred = (const float*)d_in[4];
    const float* label  = (const float*)d_in[5];
    const float* thres2 = (const float*)d_in[6];
    float* out  = (float*)d_out;
    float* base = (float*)d_ws;

    float* a      = base;
    float* m_loc  = base + SEQ;
    float* Pc     = base + 2 * (size_t)SEQ;
    float* Qc     = base + 3 * (size_t)SEQ;
    int*   openA  = (int*)(base + 4 * (size_t)SEQ);
    int*   ltLoc  = (int*)(base + 5 * (size_t)SEQ);
    int*   lfExcl = (int*)(base + 6 * (size_t)SEQ);
    float* sums   = base + 7 * (size_t)SEQ;
    float* lastm   = sums;
    float* Pch     = sums + NCH;
    float* Qch     = sums + 2 * NCH;
    float* Ech     = sums + 3 * NCH;
    float* Fch     = sums + 4 * NCH;
    int*   lastopen = (int*)(sums + 5 * NCH);
    int*   lastgate = (int*)(sums + 6 * NCH);
    int*   trigLast = (int*)(sums + 7 * NCH);
    int*   fallLast = (int*)(sums + 8 * NCH);

    k_matvec_local<<<SEQ / 16, 256, 0, stream>>>(h, W, b, u_pred, label, a,
                                                 m_loc, openA, ltLoc, lfExcl,
                                                 lastm, lastopen, lastgate, trigLast, fallLast,
                                                 out + 4 * SEQ);
    k_uphat_alpha<<<NCH, CHUNK, 0, stream>>>(u_pred, a, m_loc, openA,
                                             lastm, lastopen, lastgate,
                                             Pc, Qc, Pch, Qch, out);
    k_alpha_y<<<NCH, CHUNK, 0, stream>>>(Pc, Qc, Pch, Qch, out, Ech, Fch);
    k_yfinal_loss<<<NCH, CHUNK, 0, stream>>>(Pc, Qc, Ech, Fch, trigLast, fallLast,
                                             u_pred, label, thres2, ltLoc, lfExcl, out);
}